// Round 9
// baseline (1482.128 us; speedup 1.0000x reference)
//
#include <hip/hip_runtime.h>

#define NPTS 32768
#define DIM  512
#define KC   256

typedef short short8 __attribute__((ext_vector_type(8)));
typedef float floatx4 __attribute__((ext_vector_type(4)));
typedef float floatx16 __attribute__((ext_vector_type(16)));

static constexpr float THRESH = 1e-4f;
static constexpr float EPS_F  = 1e-6f;

__device__ __forceinline__ void f2bf2(float x, ushort& h, ushort& l) {
    unsigned u = __float_as_uint(x);
    unsigned r = ((u >> 16) & 1u) + 0x7fffu;
    ushort uh = (ushort)((u + r) >> 16);
    float xh = __uint_as_float(((unsigned)uh) << 16);
    float xl = x - xh;
    unsigned u2 = __float_as_uint(xl);
    unsigned r2 = ((u2 >> 16) & 1u) + 0x7fffu;
    h = uh;
    l = (ushort)((u2 + r2) >> 16);
}

#define SWZ(row, bc) ((bc) ^ (((row) & 7) << 4))

#define GLL(srcp, dstp)                                                        \
    __builtin_amdgcn_global_load_lds(                                          \
        (const __attribute__((address_space(1))) unsigned int*)(srcp),         \
        (__attribute__((address_space(3))) unsigned int*)(dstp), 16, 0, 0)

#define APAY 16384
#define XPAY 32768

// ---------------- x2 ----------------
__global__ __launch_bounds__(256) void x2_kernel(const float* __restrict__ X,
                                                 float* __restrict__ x2,
                                                 int* __restrict__ stop,
                                                 int* __restrict__ counter) {
    int row  = blockIdx.x * 4 + (threadIdx.x >> 6);
    int lane = threadIdx.x & 63;
    const float4* xr = reinterpret_cast<const float4*>(X + (size_t)row * DIM);
    float4 v0 = xr[lane];
    float4 v1 = xr[lane + 64];
    float s = v0.x*v0.x + v0.y*v0.y + v0.z*v0.z + v0.w*v0.w
            + v1.x*v1.x + v1.y*v1.y + v1.z*v1.z + v1.w*v1.w;
    #pragma unroll
    for (int o = 32; o; o >>= 1) s += __shfl_xor(s, o);
    if (lane == 0) x2[row] = s;
    if (blockIdx.x == 0 && threadIdx.x == 0) { *stop = 0; *counter = 0; }
}

// -------- xpose (once): Xt image (update) + Xrow image (assign) --------
__global__ __launch_bounds__(256) void xpose_kernel(const float* __restrict__ X,
                                                    char* __restrict__ Ximg,
                                                    char* __restrict__ Xrow) {
    __shared__ ushort Th[64][72];
    __shared__ ushort Tl[64][72];
    const int tid = threadIdx.x;
    const int i0 = blockIdx.x * 64, d0 = blockIdx.y * 64;
    const int g  = blockIdx.x;
    const int db = blockIdx.y >> 1;
    const int rowbase = (blockIdx.y & 1) * 64;
    const int il = tid >> 2, dq = (tid & 3) * 16;
    __align__(16) ushort hh[16], llv[16];
    #pragma unroll
    for (int j = 0; j < 4; ++j) {
        float4 v = *(const float4*)&X[(size_t)(i0 + il) * DIM + d0 + dq + j * 4];
        ushort h[4], l[4];
        f2bf2(v.x, h[0], l[0]); f2bf2(v.y, h[1], l[1]);
        f2bf2(v.z, h[2], l[2]); f2bf2(v.w, h[3], l[3]);
        #pragma unroll
        for (int c = 0; c < 4; ++c) {
            Th[dq + j * 4 + c][il] = h[c];
            Tl[dq + j * 4 + c][il] = l[c];
            hh[j * 4 + c]  = h[c];
            llv[j * 4 + c] = l[c];
        }
    }
    if (Xrow) {
        const int s0 = (tid & 3) * 2;
        char* base = Xrow + (((size_t)g * 8 + blockIdx.y) << 14) + il * 128;
        *(uint4*)(base + (((s0)     ^ (il & 7)) << 4)) = *(const uint4*)&hh[0];
        *(uint4*)(base + (((s0 + 1) ^ (il & 7)) << 4)) = *(const uint4*)&hh[8];
        *(uint4*)(base + 8192 + (((s0)     ^ (il & 7)) << 4)) = *(const uint4*)&llv[0];
        *(uint4*)(base + 8192 + (((s0 + 1) ^ (il & 7)) << 4)) = *(const uint4*)&llv[8];
    }
    __syncthreads();
    const int dl = tid >> 2, qe = (tid & 3) * 16;
    const int rowg = rowbase + dl;
    const int s0 = (tid & 3) * 2;
    char* base = Ximg + (((size_t)db * 512 + g) << 15) + rowg * 128;
    int p0 = (s0 ^ (rowg & 7)) << 4;
    int p1 = ((s0 + 1) ^ (rowg & 7)) << 4;
    *(uint4*)(base + p0)         = *(const uint4*)&Th[dl][qe];
    *(uint4*)(base + p1)         = *(const uint4*)&Th[dl][qe + 8];
    *(uint4*)(base + 16384 + p0) = *(const uint4*)&Tl[dl][qe];
    *(uint4*)(base + 16384 + p1) = *(const uint4*)&Tl[dl][qe + 8];
}

// --- prep0 (fast path, t=0 only): seed from Cinit ---
__global__ __launch_bounds__(64) void prep0_kernel(const float* __restrict__ src,
                                                   float* __restrict__ Cout0,
                                                   char* __restrict__ Cimg,
                                                   float* __restrict__ c2a,
                                                   float* __restrict__ c2b,
                                                   float* __restrict__ a_sum0,
                                                   float* __restrict__ diffp) {
    int k = blockIdx.x, t = threadIdx.x;
    const float4* s4 = reinterpret_cast<const float4*>(src + (size_t)k * DIM);
    float4*       d4 = reinterpret_cast<float4*>(Cout0 + (size_t)k * DIM);
    float s = 0.f;
    #pragma unroll
    for (int j = 0; j < 2; ++j) {
        float4 v = s4[t + 64 * j];
        d4[t + 64 * j] = v;
        s += v.x*v.x + v.y*v.y + v.z*v.z + v.w*v.w;
    }
    {
        const int d0 = t >> 3, sl = t & 7;
        const float* cs = src + (size_t)k * DIM + d0 * 64 + sl * 8;
        __align__(16) ushort h8[8], l8[8];
        #pragma unroll
        for (int e = 0; e < 8; ++e) f2bf2(cs[e], h8[e], l8[e]);
        char* base = Cimg + d0 * 65536 + k * 128 + ((sl ^ (k & 7)) << 4);
        *(uint4*)base           = *(const uint4*)h8;
        *(uint4*)(base + 32768) = *(const uint4*)l8;
    }
    #pragma unroll
    for (int o = 32; o; o >>= 1) s += __shfl_xor(s, o);
    if (t == 0) {
        c2a[k] = s;
        c2b[k] = 0.f;
        a_sum0[k] = 0.f;
        if (k == 0) { diffp[0] = 0.f; diffp[1] = 1e30f; }   // [1] = sentinel: t=0 always runs
    }
}

// --- prep (slow path, every iter) ---
__global__ __launch_bounds__(64) void prep_kernel(const float* __restrict__ src,
                                                  float* __restrict__ Cin,
                                                  ushort* __restrict__ Chg,
                                                  ushort* __restrict__ Clg,
                                                  float* __restrict__ c2,
                                                  float* __restrict__ a_sum,
                                                  float* __restrict__ diff,
                                                  const int* __restrict__ stop) {
    if (*stop) return;
    int k = blockIdx.x, t = threadIdx.x;
    const float4* s4 = reinterpret_cast<const float4*>(src + (size_t)k * DIM);
    float4*       d4 = reinterpret_cast<float4*>(Cin + (size_t)k * DIM);
    float s = 0.f;
    #pragma unroll
    for (int j = 0; j < 2; ++j) {
        float4 v = s4[t + 64 * j];
        d4[t + 64 * j] = v;
        s += v.x*v.x + v.y*v.y + v.z*v.z + v.w*v.w;
        ushort4 h, lo;
        f2bf2(v.x, h.x, lo.x);
        f2bf2(v.y, h.y, lo.y);
        f2bf2(v.z, h.z, lo.z);
        f2bf2(v.w, h.w, lo.w);
        *(ushort4*)&Chg[(size_t)k * DIM + 4 * t + 256 * j] = h;
        *(ushort4*)&Clg[(size_t)k * DIM + 4 * t + 256 * j] = lo;
    }
    #pragma unroll
    for (int o = 32; o; o >>= 1) s += __shfl_xor(s, o);
    if (t == 0) {
        c2[k] = s;
        a_sum[k] = 0.f;
        if (k == 0) *diff = 0.f;
    }
}

// ---- assign (fast): M=128, 512 thr / 8 waves, 32x32x16 MFMA (wr2 x wc4) ----
// LDS: X @0 (32KB: hi @0, lo @16384), Cb0 @32768, Cb1 @98304 = 160KB.
#define ASN_STAGE_X(D0S)                                                       \
    {                                                                          \
        const char* b0_ = Xrow + ((((size_t)(2 * g))     * 8 + (D0S)) << 14);  \
        const char* b1_ = Xrow + ((((size_t)(2 * g) + 1) * 8 + (D0S)) << 14);  \
        GLL(b0_ + tid * 16,        smem + tid * 16);                           \
        GLL(b0_ + 8192 + tid * 16, smem + 16384 + tid * 16);                   \
        GLL(b1_ + tid * 16,        smem + 8192 + tid * 16);                    \
        GLL(b1_ + 8192 + tid * 16, smem + 24576 + tid * 16);                   \
    }

#define ASN_STAGE_C(BUF, D0S)                                                  \
    {                                                                          \
        const char* cp_ = Cimg + (D0S) * 65536;                                \
        _Pragma("unroll")                                                      \
        for (int j_ = 0; j_ < 8; ++j_)                                         \
            GLL(cp_ + (j_ * 512 + tid) * 16,                                   \
                smem + (BUF) + (j_ * 512 + tid) * 16);                         \
    }

// 32x32x16: A/B frag: row = base + (l&31), k-byte = 32*kst + 16*(l>>5).
#define ASN_COMPUTE(CB)                                                        \
    _Pragma("unroll")                                                          \
    for (int kst = 0; kst < 4; ++kst) {                                        \
        int bc = 32 * kst + 16 * hi;                                           \
        short8 ah[2], al[2];                                                   \
        _Pragma("unroll")                                                      \
        for (int rb = 0; rb < 2; ++rb) {                                       \
            int r = wr * 64 + rb * 32 + lc;                                    \
            ah[rb] = *(const short8*)(smem + r * 128 + SWZ(r, bc));            \
            al[rb] = *(const short8*)(smem + 16384 + r * 128 + SWZ(r, bc));    \
        }                                                                      \
        __builtin_amdgcn_s_setprio(1);                                         \
        _Pragma("unroll")                                                      \
        for (int cb = 0; cb < 2; ++cb) {                                       \
            int cr = wc * 64 + cb * 32 + lc;                                   \
            short8 bh = *(const short8*)(smem + (CB) + cr * 128 + SWZ(cr, bc));\
            short8 bl = *(const short8*)(smem + (CB) + 32768 + cr * 128 + SWZ(cr, bc)); \
            _Pragma("unroll")                                                  \
            for (int rb = 0; rb < 2; ++rb)                                     \
                acc[rb][cb] = __builtin_amdgcn_mfma_f32_32x32x16_bf16(ah[rb], bh, acc[rb][cb], 0, 0, 0); \
            _Pragma("unroll")                                                  \
            for (int rb = 0; rb < 2; ++rb)                                     \
                acc[rb][cb] = __builtin_amdgcn_mfma_f32_32x32x16_bf16(ah[rb], bl, acc[rb][cb], 0, 0, 0); \
            _Pragma("unroll")                                                  \
            for (int rb = 0; rb < 2; ++rb)                                     \
                acc[rb][cb] = __builtin_amdgcn_mfma_f32_32x32x16_bf16(al[rb], bh, acc[rb][cb], 0, 0, 0); \
        }                                                                      \
        __builtin_amdgcn_s_setprio(0);                                         \
    }

__global__ __launch_bounds__(512, 2) void assign_fast(
        const char* __restrict__ Cimg,
        const char* __restrict__ Xrow,
        const float* __restrict__ x2,
        const float* __restrict__ c2,
        float* __restrict__ a_sum,
        char* __restrict__ Aimg,
        const float* __restrict__ Cused,
        float* __restrict__ outC,
        const float* __restrict__ diffStop,
        float* __restrict__ diffZero) {
    if (blockIdx.x == 0 && threadIdx.x == 0) *diffZero = 0.f;
    if (*diffStop <= THRESH) return;
    __shared__ __align__(16) char smem[163840];
    uint*  T    = (uint*)smem;                 // epilogue overlay: 256*133*4 = 136192
    float* Mred = (float*)(smem + 136192);     // 512 f
    float* Sred = (float*)(smem + 138240);     // 512 f

    const int tid = threadIdx.x;
    const int w   = tid >> 6;       // 0..7
    const int wr  = w >> 2;         // row-group 0..1 (64 rows each)
    const int wc  = w & 3;          // col-group 0..3 (64 cols each)
    const int l   = tid & 63;
    const int lc  = l & 31;         // 32x32 col-lane
    const int hi  = l >> 5;         // k-half / +4-row selector
    const int g   = blockIdx.x;     // 0..255
    const int i0  = g * 128;

    floatx16 acc[2][2];
    #pragma unroll
    for (int a = 0; a < 2; ++a)
        #pragma unroll
        for (int b = 0; b < 2; ++b)
            #pragma unroll
            for (int e = 0; e < 16; ++e) acc[a][b][e] = 0.f;

    // prologue: C(0)->buf0, X(0)
    ASN_STAGE_C(32768, 0);
    ASN_STAGE_X(0);
    #pragma unroll
    for (int r = 0; r < 8; ++r) {
        const int cb_off = (r & 1) ? 98304 : 32768;
        const int nb_off = (r & 1) ? 32768 : 98304;
        if (r < 7) {
            ASN_STAGE_C(nb_off, r + 1);
            // keep C(r+1)'s 8 GLLs in flight; drain C(r) + X(r)
            asm volatile("s_waitcnt vmcnt(8)" ::: "memory");
        } else {
            asm volatile("s_waitcnt vmcnt(0)" ::: "memory");
        }
        __builtin_amdgcn_s_barrier();
        ASN_COMPUTE(cb_off);
        asm volatile("s_waitcnt lgkmcnt(0)" ::: "memory");
        __builtin_amdgcn_s_barrier();
        if (r < 7) ASN_STAGE_X(r + 1);
    }

    // maintain d_out C (off the critical path: after main loop)
    if (g < 64)
        ((float4*)outC)[g * 512 + tid] = ((const float4*)Cused)[g * 512 + tid];

    // logits: L = -2*sqrt(max(x2 + c2 - 2*dot, 1e-12))
    // 32x32 C/D layout: col = lc, row = (e&3) + 8*(e>>2) + 4*hi
    float c2v[2];
    #pragma unroll
    for (int cb = 0; cb < 2; ++cb)
        c2v[cb] = c2[wc * 64 + cb * 32 + lc];

    #pragma unroll
    for (int rb = 0; rb < 2; ++rb) {
        #pragma unroll
        for (int e = 0; e < 16; ++e) {
            int rowl = wr * 64 + rb * 32 + (e & 3) + 8 * (e >> 2) + 4 * hi;
            float x2v = x2[i0 + rowl];
            float m = -3.4e38f;
            #pragma unroll
            for (int cb = 0; cb < 2; ++cb) {
                float v = x2v + c2v[cb] - 2.f * acc[rb][cb][e];
                v = fmaxf(v, 1e-12f);
                float L = -2.f * sqrtf(v);
                acc[rb][cb][e] = L;
                m = fmaxf(m, L);
            }
            #pragma unroll
            for (int o = 1; o < 32; o <<= 1) m = fmaxf(m, __shfl_xor(m, o));
            if (lc == 0) Mred[wc * 128 + rowl] = m;
        }
    }
    __syncthreads();
    float gmv[2][16];
    #pragma unroll
    for (int rb = 0; rb < 2; ++rb)
        #pragma unroll
        for (int e = 0; e < 16; ++e) {
            int rowl = wr * 64 + rb * 32 + (e & 3) + 8 * (e >> 2) + 4 * hi;
            gmv[rb][e] = fmaxf(fmaxf(Mred[rowl], Mred[128 + rowl]),
                               fmaxf(Mred[256 + rowl], Mred[384 + rowl]));
        }
    #pragma unroll
    for (int rb = 0; rb < 2; ++rb) {
        #pragma unroll
        for (int e = 0; e < 16; ++e) {
            int rowl = wr * 64 + rb * 32 + (e & 3) + 8 * (e >> 2) + 4 * hi;
            float s = 0.f;
            #pragma unroll
            for (int cb = 0; cb < 2; ++cb) {
                float p = __expf(acc[rb][cb][e] - gmv[rb][e]);
                acc[rb][cb][e] = p;
                s += p;
            }
            #pragma unroll
            for (int o = 1; o < 32; o <<= 1) s += __shfl_xor(s, o);
            if (lc == 0) Sred[wc * 128 + rowl] = s;
        }
    }
    __syncthreads();
    float cs[2] = {0.f, 0.f};
    #pragma unroll
    for (int rb = 0; rb < 2; ++rb) {
        #pragma unroll
        for (int e = 0; e < 16; ++e) {
            int rowl = wr * 64 + rb * 32 + (e & 3) + 8 * (e >> 2) + 4 * hi;
            float inv = 1.f / (Sred[rowl] + Sred[128 + rowl]
                             + Sred[256 + rowl] + Sred[384 + rowl]);
            #pragma unroll
            for (int cb = 0; cb < 2; ++cb) {
                float a = acc[rb][cb][e] * inv;
                cs[cb] += a;
                ushort h, lv;
                f2bf2(a, h, lv);
                int col = wc * 64 + cb * 32 + lc;
                T[col * 133 + (rowl ^ ((l & 7) << 3))] = (uint)h | ((uint)lv << 16);
            }
        }
    }
    #pragma unroll
    for (int cb = 0; cb < 2; ++cb)
        cs[cb] += __shfl_xor(cs[cb], 32);
    if (l < 32) {
        #pragma unroll
        for (int cb = 0; cb < 2; ++cb)
            atomicAdd(&a_sum[wc * 64 + cb * 32 + l], cs[cb]);
    }
    __syncthreads();
    {
        // writer: (col 0..255) x (plane 0..1); each covers both row-half pages
        const int col = tid & 255;
        const int pl  = tid >> 8;
        #pragma unroll
        for (int rh = 0; rh < 2; ++rh) {
            const uint* tr = T + col * 133 + rh * 64;
            char* Apay = Aimg + (((size_t)(col >> 6) * 512 + 2 * g + rh) << 14)
                       + (col & 63) * 128 + pl * 8192;
            #pragma unroll
            for (int s = 0; s < 8; ++s) {
                uint4 va = *(const uint4*)(tr + s * 8);
                uint4 vb = *(const uint4*)(tr + s * 8 + 4);
                uint4 op;
                if (pl == 0) {
                    op.x = (va.x & 0xffffu) | (va.y << 16);
                    op.y = (va.z & 0xffffu) | (va.w << 16);
                    op.z = (vb.x & 0xffffu) | (vb.y << 16);
                    op.w = (vb.z & 0xffffu) | (vb.w << 16);
                } else {
                    op.x = (va.x >> 16) | (va.y & 0xffff0000u);
                    op.y = (va.z >> 16) | (va.w & 0xffff0000u);
                    op.z = (vb.x >> 16) | (vb.y & 0xffff0000u);
                    op.w = (vb.z >> 16) | (vb.w & 0xffff0000u);
                }
                *(uint4*)(Apay + (s << 4)) = op;
            }
        }
    }
}

// ---------------- assign (fallback): manual staging, writes f32 A ----------------
__global__ __launch_bounds__(256, 2) void assign_slow(
        const float* __restrict__ X,
        const ushort* __restrict__ Chg,
        const ushort* __restrict__ Clg,
        const float* __restrict__ x2,
        const float* __restrict__ c2,
        float* __restrict__ A,
        float* __restrict__ a_sum,
        const int* __restrict__ stop) {
    if (*stop) return;
    __shared__ __align__(16) char smem[81920];
    ushort* Ch = (ushort*)smem;
    ushort* Cl = (ushort*)(smem + 32768);
    float*  Mred = (float*)(smem + 69632);
    float*  Sred = (float*)(smem + 70656);

    const int tid = threadIdx.x;
    const int w   = tid >> 6;
    const int l   = tid & 63;
    const int lw  = l & 15;
    const int lg  = l >> 4;
    const int i0  = blockIdx.x * 64;
    const int sr  = tid >> 2;
    const int ss  = tid & 3;

    floatx4 acc[4][4];
    #pragma unroll
    for (int a = 0; a < 4; ++a)
        #pragma unroll
        for (int b = 0; b < 4; ++b) acc[a][b] = (floatx4){0.f, 0.f, 0.f, 0.f};

    for (int d0 = 0; d0 < DIM; d0 += 64) {
        __syncthreads();
        #pragma unroll
        for (int j = 0; j < 4; ++j) {
            int kl = 4 * ss + 16 * j;
            float4 v = *(const float4*)&X[(size_t)(i0 + sr) * DIM + d0 + kl];
            ushort4 h, lo;
            f2bf2(v.x, h.x, lo.x);
            f2bf2(v.y, h.y, lo.y);
            f2bf2(v.z, h.z, lo.z);
            f2bf2(v.w, h.w, lo.w);
            int bc = 2 * kl;
            *(ushort4*)(smem + 65536 + sr * 128 + SWZ(sr, bc)) = h;
            *(ushort4*)(smem + 65536 + 8192 + sr * 128 + SWZ(sr, bc)) = lo;
        }
        #pragma unroll
        for (int p = 0; p < 4; ++p) {
            int cr = p * 64 + sr;
            #pragma unroll
            for (int j = 0; j < 2; ++j) {
                int kl = 8 * ss + 32 * j;
                short8 vh = *(const short8*)&Chg[(size_t)cr * DIM + d0 + kl];
                short8 vl = *(const short8*)&Clg[(size_t)cr * DIM + d0 + kl];
                int bc = 2 * kl;
                *(short8*)((char*)Ch + cr * 128 + SWZ(cr, bc)) = vh;
                *(short8*)((char*)Cl + cr * 128 + SWZ(cr, bc)) = vl;
            }
        }
        __syncthreads();
        #pragma unroll
        for (int ks = 0; ks < 2; ++ks) {
            int bc = 64 * ks + 16 * lg;
            short8 ah[4], al[4];
            #pragma unroll
            for (int rb = 0; rb < 4; ++rb) {
                int r = rb * 16 + lw;
                ah[rb] = *(const short8*)(smem + 65536 + r * 128 + SWZ(r, bc));
                al[rb] = *(const short8*)(smem + 65536 + 8192 + r * 128 + SWZ(r, bc));
            }
            #pragma unroll
            for (int cb = 0; cb < 4; ++cb) {
                int cr = w * 64 + cb * 16 + lw;
                short8 bh = *(const short8*)((char*)Ch + cr * 128 + SWZ(cr, bc));
                short8 bl = *(const short8*)((char*)Cl + cr * 128 + SWZ(cr, bc));
                #pragma unroll
                for (int rb = 0; rb < 4; ++rb)
                    acc[rb][cb] = __builtin_amdgcn_mfma_f32_16x16x32_bf16(ah[rb], bh, acc[rb][cb], 0, 0, 0);
                #pragma unroll
                for (int rb = 0; rb < 4; ++rb)
                    acc[rb][cb] = __builtin_amdgcn_mfma_f32_16x16x32_bf16(ah[rb], bl, acc[rb][cb], 0, 0, 0);
                #pragma unroll
                for (int rb = 0; rb < 4; ++rb)
                    acc[rb][cb] = __builtin_amdgcn_mfma_f32_16x16x32_bf16(al[rb], bh, acc[rb][cb], 0, 0, 0);
            }
        }
    }
    __syncthreads();

    float x2r[4][4];
    #pragma unroll
    for (int rb = 0; rb < 4; ++rb)
        #pragma unroll
        for (int j = 0; j < 4; ++j)
            x2r[rb][j] = x2[i0 + rb * 16 + lg * 4 + j];
    float c2v[4];
    #pragma unroll
    for (int cb = 0; cb < 4; ++cb)
        c2v[cb] = c2[w * 64 + cb * 16 + lw];

    #pragma unroll
    for (int rb = 0; rb < 4; ++rb) {
        #pragma unroll
        for (int j = 0; j < 4; ++j) {
            float m = -3.4e38f;
            #pragma unroll
            for (int cb = 0; cb < 4; ++cb) {
                float v = x2r[rb][j] + c2v[cb] - 2.f * acc[rb][cb][j];
                v = fmaxf(v, 1e-12f);
                float L = -2.f * sqrtf(v);
                acc[rb][cb][j] = L;
                m = fmaxf(m, L);
            }
            #pragma unroll
            for (int o = 1; o < 16; o <<= 1) m = fmaxf(m, __shfl_xor(m, o));
            if (lw == 0) Mred[w * 64 + rb * 16 + lg * 4 + j] = m;
        }
    }
    __syncthreads();
    float gm[4][4];
    #pragma unroll
    for (int rb = 0; rb < 4; ++rb)
        #pragma unroll
        for (int j = 0; j < 4; ++j) {
            int row = rb * 16 + lg * 4 + j;
            gm[rb][j] = fmaxf(fmaxf(Mred[row], Mred[64 + row]),
                              fmaxf(Mred[128 + row], Mred[192 + row]));
        }
    #pragma unroll
    for (int rb = 0; rb < 4; ++rb) {
        #pragma unroll
        for (int j = 0; j < 4; ++j) {
            float s = 0.f;
            #pragma unroll
            for (int cb = 0; cb < 4; ++cb) {
                float p = __expf(acc[rb][cb][j] - gm[rb][j]);
                acc[rb][cb][j] = p;
                s += p;
            }
            #pragma unroll
            for (int o = 1; o < 16; o <<= 1) s += __shfl_xor(s, o);
            if (lw == 0) Sred[w * 64 + rb * 16 + lg * 4 + j] = s;
        }
    }
    __syncthreads();
    float cs[4] = {0.f, 0.f, 0.f, 0.f};
    #pragma unroll
    for (int rb = 0; rb < 4; ++rb) {
        #pragma unroll
        for (int j = 0; j < 4; ++j) {
            int row = rb * 16 + lg * 4 + j;
            float inv = 1.f / (Sred[row] + Sred[64 + row] + Sred[128 + row] + Sred[192 + row]);
            #pragma unroll
            for (int cb = 0; cb < 4; ++cb) {
                float a = acc[rb][cb][j] * inv;
                cs[cb] += a;
                A[(size_t)(i0 + row) * KC + w * 64 + cb * 16 + lw] = a;
            }
        }
    }
    #pragma unroll
    for (int cb = 0; cb < 4; ++cb) {
        float v = cs[cb];
        v += __shfl_xor(v, 16);
        v += __shfl_xor(v, 32);
        cs[cb] = v;
    }
    if (l < 16) {
        #pragma unroll
        for (int cb = 0; cb < 4; ++cb)
            atomicAdd(&a_sum[w * 64 + cb * 16 + lw], cs[cb]);
    }
}

// ---- emit (once): A f32 <- Aimg ----
__global__ __launch_bounds__(256) void emit_kernel(const char* __restrict__ Aimg,
                                                   float* __restrict__ A) {
    __shared__ __align__(16) char sm[65536];
    const int g = blockIdx.x;
    const int tid = threadIdx.x;
    #pragma unroll
    for (int kb = 0; kb < 4; ++kb) {
        const char* src = Aimg + (((size_t)kb * 512 + g) << 14);
        #pragma unroll
        for (int j = 0; j < 4; ++j)
            *(uint4*)(sm + kb * 16384 + j * 4096 + tid * 16) =
                *(const uint4*)(src + j * 4096 + tid * 16);
    }
    __syncthreads();
    const int i  = tid >> 2;
    const int k0 = (tid & 3) * 64;
    const int ib = i >> 3, ie = i & 7;
    float* arow = A + (size_t)(g * 64 + i) * KC + k0;
    #pragma unroll
    for (int jq = 0; jq < 16; ++jq) {
        float4 v;
        #pragma unroll
        for (int e = 0; e < 4; ++e) {
            int k  = k0 + jq * 4 + e;
            int kb = k >> 6, kr = k & 63;
            int off = kb * 16384 + kr * 128 + ((ib ^ (kr & 7)) << 4) + 2 * ie;
            ushort h  = *(const ushort*)(sm + off);
            ushort lo = *(const ushort*)(sm + off + 8192);
            ((float*)&v)[e] = __uint_as_float((uint)h << 16) + __uint_as_float((uint)lo << 16);
        }
        *(float4*)(arow + jq * 4) = v;
    }
}

// ---- update (fast): A staged via LDS (deduped 4x wave redundancy), X reg-direct ----
__global__ __launch_bounds__(256, 3) void update_mfma(const char* __restrict__ Aimg,
                                                      const char* __restrict__ Ximg,
                                                      float* __restrict__ part,
                                                      int S,
                                                      const float* __restrict__ diffStop) {
    if (*diffStop <= THRESH) return;
    __shared__ __align__(16) char smem[32768];   // A double-buffer: 2 x 16KB
    const int f  = blockIdx.x;
    // XCD-grouping: the 16 tile-blocks (kb x db) sharing a z-chunk get
    // consecutive-mod-8-equal blockIdx -> same XCD -> shared A/X pages L2-hit.
    const int z  = f % S;
    const int t  = f / S;
    const int kb = t & 3;
    const int db = t >> 2;
    const int steps = 512 / S;
    const int tid = threadIdx.x;
    const int w   = tid >> 6;
    const int l   = tid & 63;
    const int lw  = l & 15;
    const int lg  = l >> 4;
    const char* Abase = Aimg + (((size_t)kb * 512 + (size_t)z * steps) << 14);
    const char* Xbase = Ximg + (((size_t)db * 512 + (size_t)z * steps) << 15);

    floatx4 acc[4][2];
    #pragma unroll
    for (int a = 0; a < 4; ++a)
        #pragma unroll
        for (int b = 0; b < 2; ++b) acc[a][b] = (floatx4){0.f, 0.f, 0.f, 0.f};

    // prologue: A(0) -> buf0
    #pragma unroll
    for (int j = 0; j < 4; ++j)
        GLL(Abase + j * 4096 + tid * 16, smem + j * 4096 + tid * 16);

    for (int st = 0; st < steps; ++st) {
        const int cur = (st & 1) ? 16384 : 0;
        const int nxt = (st & 1) ? 0 : 16384;
        const char* Xp = Xbase + ((size_t)st << 15);
        // X fragments (per-wave unique) -> registers, both ks halves
        short8 bh[2][2], bl[2][2];
        #pragma unroll
        for (int ks = 0; ks < 2; ++ks) {
            int bc = 64 * ks + 16 * lg;
            #pragma unroll
            for (int cb = 0; cb < 2; ++cb) {
                int rd = w * 32 + cb * 16 + lw;
                int off = rd * 128 + SWZ(rd, bc);
                bh[ks][cb] = *(const short8*)(Xp + off);
                bl[ks][cb] = *(const short8*)(Xp + 16384 + off);
            }
        }
        if (st + 1 < steps) {
            const char* Ap = Abase + ((size_t)(st + 1) << 14);
            #pragma unroll
            for (int j = 0; j < 4; ++j)
                GLL(Ap + j * 4096 + tid * 16, smem + nxt + j * 4096 + tid * 16);
            // drain A(st) + X(st); keep A(st+1)'s 4 GLLs in flight
            asm volatile("s_waitcnt vmcnt(4)" ::: "memory");
        } else {
            asm volatile("s_waitcnt vmcnt(0)" ::: "memory");
        }
        __builtin_amdgcn_s_barrier();
        #pragma unroll
        for (int ks = 0; ks < 2; ++ks) {
            int bc = 64 * ks + 16 * lg;
            short8 ah[4], al[4];
            #pragma unroll
            for (int rb = 0; rb < 4; ++rb) {
                int r = rb * 16 + lw;
                int off = r * 128 + SWZ(r, bc);
                ah[rb] = *(const short8*)(smem + cur + off);
                al[rb] = *(const short8*)(smem + cur + 8192 + off);
            }
            __builtin_amdgcn_s_setprio(1);
            #pragma unroll
            for (int cb = 0; cb < 2; ++cb) {
                #pragma unroll
                for (int rb = 0; rb < 4; ++rb)
                    acc[rb][cb] = __builtin_amdgcn_mfma_f32_16x16x32_bf16(ah[rb], bh[ks][cb], acc[rb][cb], 0, 0, 0);
                #pragma unroll
                for (int rb = 0; rb < 4; ++rb)
                    acc[rb][cb] = __builtin_amdgcn_mfma_f32_16x16x32_bf16(ah[rb], bl[ks][cb], acc[rb][cb], 0, 0, 0);
                #pragma unroll
                for (int rb = 0; rb < 4; ++rb)
                    acc[rb][cb] = __builtin_amdgcn_mfma_f32_16x16x32_bf16(al[rb], bh[ks][cb], acc[rb][cb], 0, 0, 0);
            }
            __builtin_amdgcn_s_setprio(0);
        }
        asm volatile("s_waitcnt lgkmcnt(0)" ::: "memory");
        __builtin_amdgcn_s_barrier();
    }

    float* pb = part + (size_t)z * (KC * DIM);
    #pragma unroll
    for (int rb = 0; rb < 4; ++rb)
        #pragma unroll
        for (int cb = 0; cb < 2; ++cb) {
            int kbr = kb * 64 + rb * 16 + lg * 4;
            int d   = db * 128 + w * 32 + cb * 16 + lw;
            #pragma unroll
            for (int j = 0; j < 4; ++j)
                pb[(size_t)(kbr + j) * DIM + d] = acc[rb][cb][j];
        }
}

// ---------------- update (f32 fallback) ----------------
#define UIC  32
#define ALD  68
#define XLD2 136

__global__ __launch_bounds__(256) void update_f32(const float* __restrict__ A,
                                                  const float* __restrict__ X,
                                                  float* __restrict__ part,
                                                  int ichunk,
                                                  const int* __restrict__ stop) {
    if (*stop) return;
    __shared__ __align__(16) float As[UIC][ALD];
    __shared__ __align__(16) float Xs[UIC][XLD2];
    const int tid  = threadIdx.x;
    const int tk   = tid & 15;
    const int td   = tid >> 4;
    const int k0   = blockIdx.x * 64;
    const int d0   = blockIdx.y * 128;
    const int ibeg = blockIdx.z * ichunk;

    float acc[4][8];
    #pragma unroll
    for (int a = 0; a < 4; ++a)
        #pragma unroll
        for (int b = 0; b < 8; ++b) acc[a][b] = 0.f;

    for (int ii = 0; ii < ichunk; ii += UIC) {
        __syncthreads();
        #pragma unroll
        for (int e = tid; e < UIC * 64; e += 256) {
            int k = e & 63, i = e >> 6;
            As[i][k] = A[(size_t)(ibeg + ii + i) * KC + k0 + k];
        }
        #pragma unroll
        for (int e = tid; e < UIC * 128; e += 256) {
            int d = e & 127, i = e >> 7;
            Xs[i][d] = X[(size_t)(ibeg + ii + i) * DIM + d0 + d];
        }
        __syncthreads();
        #pragma unroll 4
        for (int i = 0; i < UIC; ++i) {
            float av[4], xv[8];
            *(float4*)av      = *(const float4*)&As[i][tk * 4];
            *(float4*)&xv[0]  = *(const float4*)&Xs[i][td * 8];
            *(float4*)&xv[4]  = *(const float4*)&Xs[i][td * 8 + 4];
            #pragma unroll
            for (int a = 0; a < 4; ++a)
                #pragma unroll
                for (int b = 0; b < 8; ++b)
                    acc[a][b] = fmaf(av[a], xv[b], acc[a][b]);
        }
    }
    float* pb = part + (size_t)blockIdx.z * (KC * DIM);
    #pragma unroll
    for (int a = 0; a < 4; ++a) {
        float* prow = pb + (size_t)(k0 + tk * 4 + a) * DIM + d0 + td * 8;
        *(float4*)&prow[0] = *(float4*)&acc[a][0];
        *(float4*)&prow[4] = *(float4*)&acc[a][4];
    }
}

// -- reduce_fused (fast): float4-vectorized; Cnext, diff + next-iter prep --
__global__ __launch_bounds__(256) void reduce_fused(const float* __restrict__ part,
                                                    const float* __restrict__ a_sumR,
                                                    const float* __restrict__ Cprev,
                                                    float* __restrict__ Cnext,
                                                    float* __restrict__ c2W,
                                                    float* __restrict__ c2Z,
                                                    float* __restrict__ a_sumZ,
                                                    float* __restrict__ diffR,
                                                    const float* __restrict__ diffStop,
                                                    char* __restrict__ Cimg,
                                                    int S) {
    if (*diffStop <= THRESH) return;
    const int tid = threadIdx.x;
    const int idx4 = blockIdx.x * 256 + tid;     // grid 128 blocks, 4 floats/thread
    const int idx  = idx4 * 4;
    float4 s = {0.f, 0.f, 0.f, 0.f};
    for (int p = 0; p < S; ++p) {
        float4 v = *(const float4*)&part[(size_t)p * (KC * DIM) + idx];
        s.x += v.x; s.y += v.y; s.z += v.z; s.w += v.w;
    }
    int k = idx >> 9;
    float den = a_sumR[k] + EPS_F;
    float4 v4;
    v4.x = s.x / den; v4.y = s.y / den; v4.z = s.z / den; v4.w = s.w / den;
    *(float4*)&Cnext[idx] = v4;
    // next-iter prep: bf16 hi/lo into C-image (4 consecutive d share one 16B slot)
    {
        int d = idx & 511;
        ushort4 h, lo;
        f2bf2(v4.x, h.x, lo.x);
        f2bf2(v4.y, h.y, lo.y);
        f2bf2(v4.z, h.z, lo.z);
        f2bf2(v4.w, h.w, lo.w);
        char* cb = Cimg + (d >> 6) * 65536 + k * 128
                 + ((((d >> 3) & 7) ^ (k & 7)) << 4) + (d & 7) * 2;
        *(ushort4*)cb           = h;
        *(ushort4*)(cb + 32768) = lo;
    }
    // zero ping-pong buffers for iter t+1 (safe: their readers/writers all done)
    if (blockIdx.x == 1) a_sumZ[tid] = 0.f;
    if (blockIdx.x == 2) c2Z[tid] = 0.f;
    // diff partial + c2 partial (wave covers 256 consecutive d within one k)
    float4 cp = *(const float4*)&Cprev[idx];
    float d = fabsf(v4.x - cp.x) + fabsf(v4.y - cp.y)
            + fabsf(v4.z - cp.z) + fabsf(v4.w - cp.w);
    float vv = v4.x*v4.x + v4.y*v4.y + v4.z*v4.z + v4.w*v4.w;
    #pragma unroll
    for (int o = 32; o; o >>= 1) { d += __shfl_xor(d, o); vv += __shfl_xor(vv, o); }
    if ((tid & 63) == 0) {
        atomicAdd(diffR, d);
        atomicAdd(&c2W[k], vv);
    }
}

// -- reduce (slow fallback): as before --
__global__ __launch_bounds__(256) void reduce_slow(const float* __restrict__ part,
                                                   const float* __restrict__ a_sum,
                                                   const float* __restrict__ Cin,
                                                   float* __restrict__ Cout,
                                                   float* __restrict__ diff,
                                                   int* __restrict__ counter,
                                                   int* __restrict__ stop,
                                                   int S) {
    if (*stop) return;
    int idx = blockIdx.x * 256 + threadIdx.x;
    float s = 0.f;
    for (int p = 0; p < S; ++p) s += part[(size_t)p * (KC * DIM) + idx];
    int k = idx >> 9;
    float v = s / (a_sum[k] + EPS_F);
    Cout[idx] = v;
    float d = fabsf(v - Cin[idx]);
    #pragma unroll
    for (int o = 32; o; o >>= 1) d += __shfl_xor(d, o);
    if ((threadIdx.x & 63) == 0) atomicAdd(diff, d);
    __syncthreads();
    if (threadIdx.x == 0) {
        __threadfence();
        int done = atomicAdd(counter, 1);
        if (done == (int)gridDim.x - 1) {
            __threadfence();
            float dv = atomicAdd(diff, 0.f);
            if (dv <= THRESH) *stop = 1;
            *counter = 0;
        }
    }
}

extern "C" void kernel_launch(void* const* d_in, const int* in_sizes, int n_in,
                              void* d_out, int out_size, void* d_ws, size_t ws_size,
                              hipStream_t stream) {
    const float* X     = (const float*)d_in[0];
    const float* Cinit = (const float*)d_in[1];
    float* out = (float*)d_out;
    float* outC = out;                 // [256*512]
    float* A    = out + KC * DIM;      // [32768*256]

    char* p = (char*)d_ws;
    float* x2      = (float*)p;  p += NPTS * 4;
    float* c2b0    = (float*)p;  p += 1024;
    float* c2b1    = (float*)p;  p += 1024;
    float* asum0   = (float*)p;  p += 1024;
    float* asum1   = (float*)p;  p += 1024;
    float* diffp   = (float*)p;          // diff[0]@0, diff[1]@4
    int*   stop    = (int*)(p + 16);
    int*   counter = (int*)(p + 20);  p += 64;
    float* CoutA   = (float*)p;  p += (size_t)KC * DIM * 4;
    float* CoutB   = (float*)p;  p += (size_t)KC * DIM * 4;
    ushort* Chg    = (ushort*)p; p += (size_t)KC * DIM * 2;
    ushort* Clg    = (ushort*)p; p += (size_t)KC * DIM * 2;
    char* Cimg     = p;          p += 524288;
    char* planes = p;
    char* Ximg   = p;          p += (size_t)4 * 512 * XPAY;   // 64 MB
    char* Aimg   = p;          p += (size_t)4 * 512 * APAY;   // 32 MB
    float* partF = (float*)p;
    char* Xrow   = p + (size_t)32 * KC * DIM * 4;             // after S=32 part (16 MB)
    float* partS = (float*)planes;

    size_t fixedS  = (size_t)(planes - (char*)d_ws);
    size_t needT2  = (size_t)(Xrow - (char*)d_ws) + (size_t)512 * 8 * 16384;  // + 64MB
    const size_t PART1 = (size_t)KC * DIM * 4;
    bool tier2 = ws_size >= needT2;
    int S = 32;
    if (!tier2) { while (S > 1 && fixedS + (size_t)S * PART1 > ws_size) S >>= 1; }
    int ichunk = NPTS / S;
    float* part = tier2 ? partF : partS;

    x2_kernel<<<NPTS / 4, 256, 0, stream>>>(X, x2, stop, counter);
    if (tier2) {
        xpose_kernel<<<dim3(NPTS / 64, DIM / 64), 256, 0, stream>>>(X, Ximg, Xrow);
        prep0_kernel<<<KC, 64, 0, stream>>>(Cinit, CoutA, Cimg, c2b0, c2b1, asum0, diffp);
        for (int t = 0; t < 26; ++t) {
            int par = t & 1;
            float* c2R   = par ? c2b1 : c2b0;
            float* c2Wn  = par ? c2b0 : c2b1;
            float* asR   = par ? asum1 : asum0;
            float* asZ   = par ? asum0 : asum1;
            float* Cuse  = par ? CoutB : CoutA;
            float* Cnext = par ? CoutA : CoutB;
            float* dStop = diffp + (par ^ 1);   // diff from iter t-1 (sentinel at t=0)
            float* dAcc  = diffp + par;         // zeroed by assign, accumulated by reduce
            assign_fast<<<NPTS / 128, 512, 0, stream>>>(Cimg, Xrow,
                                                        x2, c2R, asR, Aimg, Cuse, outC,
                                                        dStop, dAcc);
            update_mfma<<<16 * S, 256, 0, stream>>>(Aimg, Ximg, part, S, dStop);
            reduce_fused<<<KC * DIM / 1024, 256, 0, stream>>>(part, asR, Cuse, Cnext,
                                                              c2Wn, c2R, asZ,
                                                              dAcc, dStop, Cimg, S);
        }
        emit_kernel<<<512, 256, 0, stream>>>(Aimg, A);
    } else {
        for (int t = 0; t < 26; ++t) {
            prep_kernel<<<KC, 64, 0, stream>>>(t == 0 ? Cinit : CoutB, outC, Chg, Clg,
                                               c2b0, asum0, diffp, stop);
            assign_slow<<<NPTS / 64, 256, 0, stream>>>(X, Chg, Clg, x2, c2b0, A, asum0, stop);
            update_f32<<<dim3(KC / 64, DIM / 128, S), 256, 0, stream>>>(A, X, part, ichunk, stop);
            reduce_slow<<<KC * DIM / 256, 256, 0, stream>>>(part, asum0, outC, CoutB,
                                                            diffp, counter, stop, S);
        }
    }
}

// Round 10
// 1370.739 us; speedup vs baseline: 1.0813x; 1.0813x over previous
//
#include <hip/hip_runtime.h>

#define NPTS 32768
#define DIM  512
#define KC   256

typedef short short8 __attribute__((ext_vector_type(8)));
typedef float floatx4 __attribute__((ext_vector_type(4)));

static constexpr float THRESH = 1e-4f;
static constexpr float EPS_F  = 1e-6f;

__device__ __forceinline__ void f2bf2(float x, ushort& h, ushort& l) {
    unsigned u = __float_as_uint(x);
    unsigned r = ((u >> 16) & 1u) + 0x7fffu;
    ushort uh = (ushort)((u + r) >> 16);
    float xh = __uint_as_float(((unsigned)uh) << 16);
    float xl = x - xh;
    unsigned u2 = __float_as_uint(xl);
    unsigned r2 = ((u2 >> 16) & 1u) + 0x7fffu;
    h = uh;
    l = (ushort)((u2 + r2) >> 16);
}

#define SWZ(row, bc) ((bc) ^ (((row) & 7) << 4))

#define GLL(srcp, dstp)                                                        \
    __builtin_amdgcn_global_load_lds(                                          \
        (const __attribute__((address_space(1))) unsigned int*)(srcp),         \
        (__attribute__((address_space(3))) unsigned int*)(dstp), 16, 0, 0)

#define APAY 16384
#define XPAY 32768

// ---------------- x2 ----------------
__global__ __launch_bounds__(256) void x2_kernel(const float* __restrict__ X,
                                                 float* __restrict__ x2,
                                                 int* __restrict__ stop,
                                                 int* __restrict__ counter) {
    int row  = blockIdx.x * 4 + (threadIdx.x >> 6);
    int lane = threadIdx.x & 63;
    const float4* xr = reinterpret_cast<const float4*>(X + (size_t)row * DIM);
    float4 v0 = xr[lane];
    float4 v1 = xr[lane + 64];
    float s = v0.x*v0.x + v0.y*v0.y + v0.z*v0.z + v0.w*v0.w
            + v1.x*v1.x + v1.y*v1.y + v1.z*v1.z + v1.w*v1.w;
    #pragma unroll
    for (int o = 32; o; o >>= 1) s += __shfl_xor(s, o);
    if (lane == 0) x2[row] = s;
    if (blockIdx.x == 0 && threadIdx.x == 0) { *stop = 0; *counter = 0; }
}

// -------- xpose (once): Xt image (update) + Xrow image (assign) --------
__global__ __launch_bounds__(256) void xpose_kernel(const float* __restrict__ X,
                                                    char* __restrict__ Ximg,
                                                    char* __restrict__ Xrow) {
    __shared__ ushort Th[64][72];
    __shared__ ushort Tl[64][72];
    const int tid = threadIdx.x;
    const int i0 = blockIdx.x * 64, d0 = blockIdx.y * 64;
    const int g  = blockIdx.x;
    const int db = blockIdx.y >> 1;
    const int rowbase = (blockIdx.y & 1) * 64;
    const int il = tid >> 2, dq = (tid & 3) * 16;
    __align__(16) ushort hh[16], llv[16];
    #pragma unroll
    for (int j = 0; j < 4; ++j) {
        float4 v = *(const float4*)&X[(size_t)(i0 + il) * DIM + d0 + dq + j * 4];
        ushort h[4], l[4];
        f2bf2(v.x, h[0], l[0]); f2bf2(v.y, h[1], l[1]);
        f2bf2(v.z, h[2], l[2]); f2bf2(v.w, h[3], l[3]);
        #pragma unroll
        for (int c = 0; c < 4; ++c) {
            Th[dq + j * 4 + c][il] = h[c];
            Tl[dq + j * 4 + c][il] = l[c];
            hh[j * 4 + c]  = h[c];
            llv[j * 4 + c] = l[c];
        }
    }
    if (Xrow) {
        const int s0 = (tid & 3) * 2;
        char* base = Xrow + (((size_t)g * 8 + blockIdx.y) << 14) + il * 128;
        *(uint4*)(base + (((s0)     ^ (il & 7)) << 4)) = *(const uint4*)&hh[0];
        *(uint4*)(base + (((s0 + 1) ^ (il & 7)) << 4)) = *(const uint4*)&hh[8];
        *(uint4*)(base + 8192 + (((s0)     ^ (il & 7)) << 4)) = *(const uint4*)&llv[0];
        *(uint4*)(base + 8192 + (((s0 + 1) ^ (il & 7)) << 4)) = *(const uint4*)&llv[8];
    }
    __syncthreads();
    const int dl = tid >> 2, qe = (tid & 3) * 16;
    const int rowg = rowbase + dl;
    const int s0 = (tid & 3) * 2;
    char* base = Ximg + (((size_t)db * 512 + g) << 15) + rowg * 128;
    int p0 = (s0 ^ (rowg & 7)) << 4;
    int p1 = ((s0 + 1) ^ (rowg & 7)) << 4;
    *(uint4*)(base + p0)         = *(const uint4*)&Th[dl][qe];
    *(uint4*)(base + p1)         = *(const uint4*)&Th[dl][qe + 8];
    *(uint4*)(base + 16384 + p0) = *(const uint4*)&Tl[dl][qe];
    *(uint4*)(base + 16384 + p1) = *(const uint4*)&Tl[dl][qe + 8];
}

// --- prep0 (fast path, t=0 only): seed from Cinit ---
__global__ __launch_bounds__(64) void prep0_kernel(const float* __restrict__ src,
                                                   float* __restrict__ Cout0,
                                                   char* __restrict__ Cimg,
                                                   float* __restrict__ c2a,
                                                   float* __restrict__ c2b,
                                                   float* __restrict__ a_sum0,
                                                   float* __restrict__ diffp) {
    int k = blockIdx.x, t = threadIdx.x;
    const float4* s4 = reinterpret_cast<const float4*>(src + (size_t)k * DIM);
    float4*       d4 = reinterpret_cast<float4*>(Cout0 + (size_t)k * DIM);
    float s = 0.f;
    #pragma unroll
    for (int j = 0; j < 2; ++j) {
        float4 v = s4[t + 64 * j];
        d4[t + 64 * j] = v;
        s += v.x*v.x + v.y*v.y + v.z*v.z + v.w*v.w;
    }
    {
        const int d0 = t >> 3, sl = t & 7;
        const float* cs = src + (size_t)k * DIM + d0 * 64 + sl * 8;
        __align__(16) ushort h8[8], l8[8];
        #pragma unroll
        for (int e = 0; e < 8; ++e) f2bf2(cs[e], h8[e], l8[e]);
        char* base = Cimg + d0 * 65536 + k * 128 + ((sl ^ (k & 7)) << 4);
        *(uint4*)base           = *(const uint4*)h8;
        *(uint4*)(base + 32768) = *(const uint4*)l8;
    }
    #pragma unroll
    for (int o = 32; o; o >>= 1) s += __shfl_xor(s, o);
    if (t == 0) {
        c2a[k] = s;
        c2b[k] = 0.f;
        a_sum0[k] = 0.f;
        if (k == 0) { diffp[0] = 0.f; diffp[1] = 1e30f; }   // [1] = sentinel: t=0 always runs
    }
}

// --- prep (slow path, every iter) ---
__global__ __launch_bounds__(64) void prep_kernel(const float* __restrict__ src,
                                                  float* __restrict__ Cin,
                                                  ushort* __restrict__ Chg,
                                                  ushort* __restrict__ Clg,
                                                  float* __restrict__ c2,
                                                  float* __restrict__ a_sum,
                                                  float* __restrict__ diff,
                                                  const int* __restrict__ stop) {
    if (*stop) return;
    int k = blockIdx.x, t = threadIdx.x;
    const float4* s4 = reinterpret_cast<const float4*>(src + (size_t)k * DIM);
    float4*       d4 = reinterpret_cast<float4*>(Cin + (size_t)k * DIM);
    float s = 0.f;
    #pragma unroll
    for (int j = 0; j < 2; ++j) {
        float4 v = s4[t + 64 * j];
        d4[t + 64 * j] = v;
        s += v.x*v.x + v.y*v.y + v.z*v.z + v.w*v.w;
        ushort4 h, lo;
        f2bf2(v.x, h.x, lo.x);
        f2bf2(v.y, h.y, lo.y);
        f2bf2(v.z, h.z, lo.z);
        f2bf2(v.w, h.w, lo.w);
        *(ushort4*)&Chg[(size_t)k * DIM + 4 * t + 256 * j] = h;
        *(ushort4*)&Clg[(size_t)k * DIM + 4 * t + 256 * j] = lo;
    }
    #pragma unroll
    for (int o = 32; o; o >>= 1) s += __shfl_xor(s, o);
    if (t == 0) {
        c2[k] = s;
        a_sum[k] = 0.f;
        if (k == 0) *diff = 0.f;
    }
}

// -------- assign (fast): M=128, 512 thr / 8 waves (wr2 x wc4, rb4 x cb4) --------
// LDS: X @0 (32KB: hi rows0-127 @0, lo @16384), Cb0 @32768, Cb1 @98304 = 160KB.
#define ASN_STAGE_X(D0S)                                                       \
    {                                                                          \
        const char* b0_ = Xrow + ((((size_t)(2 * g))     * 8 + (D0S)) << 14);  \
        const char* b1_ = Xrow + ((((size_t)(2 * g) + 1) * 8 + (D0S)) << 14);  \
        GLL(b0_ + tid * 16,        smem + tid * 16);                           \
        GLL(b0_ + 8192 + tid * 16, smem + 16384 + tid * 16);                   \
        GLL(b1_ + tid * 16,        smem + 8192 + tid * 16);                    \
        GLL(b1_ + 8192 + tid * 16, smem + 24576 + tid * 16);                   \
    }

#define ASN_STAGE_C(BUF, D0S)                                                  \
    {                                                                          \
        const char* cp_ = Cimg + (D0S) * 65536;                                \
        _Pragma("unroll")                                                      \
        for (int j_ = 0; j_ < 8; ++j_)                                         \
            GLL(cp_ + (j_ * 512 + tid) * 16,                                   \
                smem + (BUF) + (j_ * 512 + tid) * 16);                         \
    }

#define ASN_COMPUTE(CB)                                                        \
    _Pragma("unroll")                                                          \
    for (int ks = 0; ks < 2; ++ks) {                                           \
        int bc = 64 * ks + 16 * lg;                                            \
        short8 ah[4], al[4];                                                   \
        _Pragma("unroll")                                                      \
        for (int rb = 0; rb < 4; ++rb) {                                       \
            int r = wr * 64 + rb * 16 + lw;                                    \
            ah[rb] = *(const short8*)(smem + r * 128 + SWZ(r, bc));            \
            al[rb] = *(const short8*)(smem + 16384 + r * 128 + SWZ(r, bc));    \
        }                                                                      \
        __builtin_amdgcn_s_setprio(1);                                         \
        _Pragma("unroll")                                                      \
        for (int cb = 0; cb < 4; ++cb) {                                       \
            int cr = wc * 64 + cb * 16 + lw;                                   \
            short8 bh = *(const short8*)(smem + (CB) + cr * 128 + SWZ(cr, bc));\
            short8 bl = *(const short8*)(smem + (CB) + 32768 + cr * 128 + SWZ(cr, bc)); \
            _Pragma("unroll")                                                  \
            for (int rb = 0; rb < 4; ++rb)                                     \
                acc[rb][cb] = __builtin_amdgcn_mfma_f32_16x16x32_bf16(ah[rb], bh, acc[rb][cb], 0, 0, 0); \
            _Pragma("unroll")                                                  \
            for (int rb = 0; rb < 4; ++rb)                                     \
                acc[rb][cb] = __builtin_amdgcn_mfma_f32_16x16x32_bf16(ah[rb], bl, acc[rb][cb], 0, 0, 0); \
            _Pragma("unroll")                                                  \
            for (int rb = 0; rb < 4; ++rb)                                     \
                acc[rb][cb] = __builtin_amdgcn_mfma_f32_16x16x32_bf16(al[rb], bh, acc[rb][cb], 0, 0, 0); \
        }                                                                      \
        __builtin_amdgcn_s_setprio(0);                                         \
    }

__global__ __launch_bounds__(512, 2) void assign_fast(
        const char* __restrict__ Cimg,
        const char* __restrict__ Xrow,
        const float* __restrict__ x2,
        const float* __restrict__ c2,
        float* __restrict__ a_sum,
        char* __restrict__ Aimg,
        const float* __restrict__ Cused,
        float* __restrict__ outC,
        const float* __restrict__ diffStop,
        float* __restrict__ diffZero) {
    // diff-sentinel stopping: zero the accumulator for THIS iter's reduce;
    // stop if last iter's diff is below threshold (0-write keeps stop sticky).
    if (blockIdx.x == 0 && threadIdx.x == 0) *diffZero = 0.f;
    if (*diffStop <= THRESH) return;
    __shared__ __align__(16) char smem[163840];
    uint*  T    = (uint*)smem;                 // epilogue overlay: 256*133*4 = 136192
    float* Mred = (float*)(smem + 136192);     // 512 f
    float* Sred = (float*)(smem + 138240);     // 512 f

    const int tid = threadIdx.x;
    const int w   = tid >> 6;       // 0..7
    const int wr  = w >> 2;         // row-group 0..1 (64 rows each)
    const int wc  = w & 3;          // col-group 0..3 (64 cols each)
    const int l   = tid & 63;
    const int lw  = l & 15;
    const int lg  = l >> 4;
    const int g   = blockIdx.x;     // 0..255
    const int i0  = g * 128;

    floatx4 acc[4][4];
    #pragma unroll
    for (int a = 0; a < 4; ++a)
        #pragma unroll
        for (int b = 0; b < 4; ++b) acc[a][b] = (floatx4){0.f, 0.f, 0.f, 0.f};

    // prologue: C(0)->buf0, X(0)
    ASN_STAGE_C(32768, 0);
    ASN_STAGE_X(0);
    #pragma unroll
    for (int r = 0; r < 8; ++r) {
        const int cb_off = (r & 1) ? 98304 : 32768;
        const int nb_off = (r & 1) ? 32768 : 98304;
        if (r < 7) {
            ASN_STAGE_C(nb_off, r + 1);
            // keep C(r+1)'s 8 GLLs in flight; drain C(r) + X(r)
            asm volatile("s_waitcnt vmcnt(8)" ::: "memory");
        } else {
            asm volatile("s_waitcnt vmcnt(0)" ::: "memory");
        }
        __builtin_amdgcn_s_barrier();
        ASN_COMPUTE(cb_off);
        asm volatile("s_waitcnt lgkmcnt(0)" ::: "memory");
        __builtin_amdgcn_s_barrier();
        if (r < 7) ASN_STAGE_X(r + 1);
    }

    // maintain d_out C = the C used by the last executed assignment
    // (after the main loop: overlaps the epilogue instead of the staging prologue)
    if (g < 64)
        ((float4*)outC)[g * 512 + tid] = ((const float4*)Cused)[g * 512 + tid];

    // logits: L = -2*sqrt(max(x2 + c2 - 2*dot, 1e-12))
    float x2r[4][4];
    #pragma unroll
    for (int rb = 0; rb < 4; ++rb)
        #pragma unroll
        for (int j = 0; j < 4; ++j)
            x2r[rb][j] = x2[i0 + wr * 64 + rb * 16 + lg * 4 + j];
    float c2v[4];
    #pragma unroll
    for (int cb = 0; cb < 4; ++cb)
        c2v[cb] = c2[wc * 64 + cb * 16 + lw];

    #pragma unroll
    for (int rb = 0; rb < 4; ++rb) {
        #pragma unroll
        for (int j = 0; j < 4; ++j) {
            float m = -3.4e38f;
            #pragma unroll
            for (int cb = 0; cb < 4; ++cb) {
                float v = x2r[rb][j] + c2v[cb] - 2.f * acc[rb][cb][j];
                v = fmaxf(v, 1e-12f);
                float L = -2.f * sqrtf(v);
                acc[rb][cb][j] = L;
                m = fmaxf(m, L);
            }
            #pragma unroll
            for (int o = 1; o < 16; o <<= 1) m = fmaxf(m, __shfl_xor(m, o));
            if (lw == 0) Mred[wc * 128 + wr * 64 + rb * 16 + lg * 4 + j] = m;
        }
    }
    __syncthreads();
    float gm[4][4];
    #pragma unroll
    for (int rb = 0; rb < 4; ++rb)
        #pragma unroll
        for (int j = 0; j < 4; ++j) {
            int row = wr * 64 + rb * 16 + lg * 4 + j;
            gm[rb][j] = fmaxf(fmaxf(Mred[row], Mred[128 + row]),
                              fmaxf(Mred[256 + row], Mred[384 + row]));
        }
    #pragma unroll
    for (int rb = 0; rb < 4; ++rb) {
        #pragma unroll
        for (int j = 0; j < 4; ++j) {
            float s = 0.f;
            #pragma unroll
            for (int cb = 0; cb < 4; ++cb) {
                float p = __expf(acc[rb][cb][j] - gm[rb][j]);
                acc[rb][cb][j] = p;
                s += p;
            }
            #pragma unroll
            for (int o = 1; o < 16; o <<= 1) s += __shfl_xor(s, o);
            if (lw == 0) Sred[wc * 128 + wr * 64 + rb * 16 + lg * 4 + j] = s;
        }
    }
    __syncthreads();
    float cs[4] = {0.f, 0.f, 0.f, 0.f};
    #pragma unroll
    for (int rb = 0; rb < 4; ++rb) {
        #pragma unroll
        for (int j = 0; j < 4; ++j) {
            int row = wr * 64 + rb * 16 + lg * 4 + j;
            float inv = 1.f / (Sred[row] + Sred[128 + row] + Sred[256 + row] + Sred[384 + row]);
            #pragma unroll
            for (int cb = 0; cb < 4; ++cb) {
                float a = acc[rb][cb][j] * inv;
                cs[cb] += a;
                ushort h, lv;
                f2bf2(a, h, lv);
                int col = wc * 64 + cb * 16 + lw;
                T[col * 133 + (row ^ ((lw & 7) << 3))] = (uint)h | ((uint)lv << 16);
            }
        }
    }
    #pragma unroll
    for (int cb = 0; cb < 4; ++cb) {
        float v = cs[cb];
        v += __shfl_xor(v, 16);
        v += __shfl_xor(v, 32);
        cs[cb] = v;
    }
    if (l < 16) {
        #pragma unroll
        for (int cb = 0; cb < 4; ++cb)
            atomicAdd(&a_sum[wc * 64 + cb * 16 + lw], cs[cb]);
    }
    __syncthreads();
    {
        // writer: (col 0..255) x (plane 0..1); each covers both row-half pages
        const int col = tid & 255;
        const int pl  = tid >> 8;
        #pragma unroll
        for (int rh = 0; rh < 2; ++rh) {
            const uint* tr = T + col * 133 + rh * 64;
            char* Apay = Aimg + (((size_t)(col >> 6) * 512 + 2 * g + rh) << 14)
                       + (col & 63) * 128 + pl * 8192;
            #pragma unroll
            for (int s = 0; s < 8; ++s) {
                uint4 va = *(const uint4*)(tr + s * 8);
                uint4 vb = *(const uint4*)(tr + s * 8 + 4);
                uint4 op;
                if (pl == 0) {
                    op.x = (va.x & 0xffffu) | (va.y << 16);
                    op.y = (va.z & 0xffffu) | (va.w << 16);
                    op.z = (vb.x & 0xffffu) | (vb.y << 16);
                    op.w = (vb.z & 0xffffu) | (vb.w << 16);
                } else {
                    op.x = (va.x >> 16) | (va.y & 0xffff0000u);
                    op.y = (va.z >> 16) | (va.w & 0xffff0000u);
                    op.z = (vb.x >> 16) | (vb.y & 0xffff0000u);
                    op.w = (vb.z >> 16) | (vb.w & 0xffff0000u);
                }
                *(uint4*)(Apay + (s << 4)) = op;
            }
        }
    }
}

// ---------------- assign (fallback): manual staging, writes f32 A ----------------
__global__ __launch_bounds__(256, 2) void assign_slow(
        const float* __restrict__ X,
        const ushort* __restrict__ Chg,
        const ushort* __restrict__ Clg,
        const float* __restrict__ x2,
        const float* __restrict__ c2,
        float* __restrict__ A,
        float* __restrict__ a_sum,
        const int* __restrict__ stop) {
    if (*stop) return;
    __shared__ __align__(16) char smem[81920];
    ushort* Ch = (ushort*)smem;
    ushort* Cl = (ushort*)(smem + 32768);
    float*  Mred = (float*)(smem + 69632);
    float*  Sred = (float*)(smem + 70656);

    const int tid = threadIdx.x;
    const int w   = tid >> 6;
    const int l   = tid & 63;
    const int lw  = l & 15;
    const int lg  = l >> 4;
    const int i0  = blockIdx.x * 64;
    const int sr  = tid >> 2;
    const int ss  = tid & 3;

    floatx4 acc[4][4];
    #pragma unroll
    for (int a = 0; a < 4; ++a)
        #pragma unroll
        for (int b = 0; b < 4; ++b) acc[a][b] = (floatx4){0.f, 0.f, 0.f, 0.f};

    for (int d0 = 0; d0 < DIM; d0 += 64) {
        __syncthreads();
        #pragma unroll
        for (int j = 0; j < 4; ++j) {
            int kl = 4 * ss + 16 * j;
            float4 v = *(const float4*)&X[(size_t)(i0 + sr) * DIM + d0 + kl];
            ushort4 h, lo;
            f2bf2(v.x, h.x, lo.x);
            f2bf2(v.y, h.y, lo.y);
            f2bf2(v.z, h.z, lo.z);
            f2bf2(v.w, h.w, lo.w);
            int bc = 2 * kl;
            *(ushort4*)(smem + 65536 + sr * 128 + SWZ(sr, bc)) = h;
            *(ushort4*)(smem + 65536 + 8192 + sr * 128 + SWZ(sr, bc)) = lo;
        }
        #pragma unroll
        for (int p = 0; p < 4; ++p) {
            int cr = p * 64 + sr;
            #pragma unroll
            for (int j = 0; j < 2; ++j) {
                int kl = 8 * ss + 32 * j;
                short8 vh = *(const short8*)&Chg[(size_t)cr * DIM + d0 + kl];
                short8 vl = *(const short8*)&Clg[(size_t)cr * DIM + d0 + kl];
                int bc = 2 * kl;
                *(short8*)((char*)Ch + cr * 128 + SWZ(cr, bc)) = vh;
                *(short8*)((char*)Cl + cr * 128 + SWZ(cr, bc)) = vl;
            }
        }
        __syncthreads();
        #pragma unroll
        for (int ks = 0; ks < 2; ++ks) {
            int bc = 64 * ks + 16 * lg;
            short8 ah[4], al[4];
            #pragma unroll
            for (int rb = 0; rb < 4; ++rb) {
                int r = rb * 16 + lw;
                ah[rb] = *(const short8*)(smem + 65536 + r * 128 + SWZ(r, bc));
                al[rb] = *(const short8*)(smem + 65536 + 8192 + r * 128 + SWZ(r, bc));
            }
            #pragma unroll
            for (int cb = 0; cb < 4; ++cb) {
                int cr = w * 64 + cb * 16 + lw;
                short8 bh = *(const short8*)((char*)Ch + cr * 128 + SWZ(cr, bc));
                short8 bl = *(const short8*)((char*)Cl + cr * 128 + SWZ(cr, bc));
                #pragma unroll
                for (int rb = 0; rb < 4; ++rb)
                    acc[rb][cb] = __builtin_amdgcn_mfma_f32_16x16x32_bf16(ah[rb], bh, acc[rb][cb], 0, 0, 0);
                #pragma unroll
                for (int rb = 0; rb < 4; ++rb)
                    acc[rb][cb] = __builtin_amdgcn_mfma_f32_16x16x32_bf16(ah[rb], bl, acc[rb][cb], 0, 0, 0);
                #pragma unroll
                for (int rb = 0; rb < 4; ++rb)
                    acc[rb][cb] = __builtin_amdgcn_mfma_f32_16x16x32_bf16(al[rb], bh, acc[rb][cb], 0, 0, 0);
            }
        }
    }
    __syncthreads();

    float x2r[4][4];
    #pragma unroll
    for (int rb = 0; rb < 4; ++rb)
        #pragma unroll
        for (int j = 0; j < 4; ++j)
            x2r[rb][j] = x2[i0 + rb * 16 + lg * 4 + j];
    float c2v[4];
    #pragma unroll
    for (int cb = 0; cb < 4; ++cb)
        c2v[cb] = c2[w * 64 + cb * 16 + lw];

    #pragma unroll
    for (int rb = 0; rb < 4; ++rb) {
        #pragma unroll
        for (int j = 0; j < 4; ++j) {
            float m = -3.4e38f;
            #pragma unroll
            for (int cb = 0; cb < 4; ++cb) {
                float v = x2r[rb][j] + c2v[cb] - 2.f * acc[rb][cb][j];
                v = fmaxf(v, 1e-12f);
                float L = -2.f * sqrtf(v);
                acc[rb][cb][j] = L;
                m = fmaxf(m, L);
            }
            #pragma unroll
            for (int o = 1; o < 16; o <<= 1) m = fmaxf(m, __shfl_xor(m, o));
            if (lw == 0) Mred[w * 64 + rb * 16 + lg * 4 + j] = m;
        }
    }
    __syncthreads();
    float gm[4][4];
    #pragma unroll
    for (int rb = 0; rb < 4; ++rb)
        #pragma unroll
        for (int j = 0; j < 4; ++j) {
            int row = rb * 16 + lg * 4 + j;
            gm[rb][j] = fmaxf(fmaxf(Mred[row], Mred[64 + row]),
                              fmaxf(Mred[128 + row], Mred[192 + row]));
        }
    #pragma unroll
    for (int rb = 0; rb < 4; ++rb) {
        #pragma unroll
        for (int j = 0; j < 4; ++j) {
            float s = 0.f;
            #pragma unroll
            for (int cb = 0; cb < 4; ++cb) {
                float p = __expf(acc[rb][cb][j] - gm[rb][j]);
                acc[rb][cb][j] = p;
                s += p;
            }
            #pragma unroll
            for (int o = 1; o < 16; o <<= 1) s += __shfl_xor(s, o);
            if (lw == 0) Sred[w * 64 + rb * 16 + lg * 4 + j] = s;
        }
    }
    __syncthreads();
    float cs[4] = {0.f, 0.f, 0.f, 0.f};
    #pragma unroll
    for (int rb = 0; rb < 4; ++rb) {
        #pragma unroll
        for (int j = 0; j < 4; ++j) {
            int row = rb * 16 + lg * 4 + j;
            float inv = 1.f / (Sred[row] + Sred[64 + row] + Sred[128 + row] + Sred[192 + row]);
            #pragma unroll
            for (int cb = 0; cb < 4; ++cb) {
                float a = acc[rb][cb][j] * inv;
                cs[cb] += a;
                A[(size_t)(i0 + row) * KC + w * 64 + cb * 16 + lw] = a;
            }
        }
    }
    #pragma unroll
    for (int cb = 0; cb < 4; ++cb) {
        float v = cs[cb];
        v += __shfl_xor(v, 16);
        v += __shfl_xor(v, 32);
        cs[cb] = v;
    }
    if (l < 16) {
        #pragma unroll
        for (int cb = 0; cb < 4; ++cb)
            atomicAdd(&a_sum[w * 64 + cb * 16 + lw], cs[cb]);
    }
}

// ---- emit (once): A f32 <- Aimg ----
__global__ __launch_bounds__(256) void emit_kernel(const char* __restrict__ Aimg,
                                                   float* __restrict__ A) {
    __shared__ __align__(16) char sm[65536];
    const int g = blockIdx.x;
    const int tid = threadIdx.x;
    #pragma unroll
    for (int kb = 0; kb < 4; ++kb) {
        const char* src = Aimg + (((size_t)kb * 512 + g) << 14);
        #pragma unroll
        for (int j = 0; j < 4; ++j)
            *(uint4*)(sm + kb * 16384 + j * 4096 + tid * 16) =
                *(const uint4*)(src + j * 4096 + tid * 16);
    }
    __syncthreads();
    const int i  = tid >> 2;
    const int k0 = (tid & 3) * 64;
    const int ib = i >> 3, ie = i & 7;
    float* arow = A + (size_t)(g * 64 + i) * KC + k0;
    #pragma unroll
    for (int jq = 0; jq < 16; ++jq) {
        float4 v;
        #pragma unroll
        for (int e = 0; e < 4; ++e) {
            int k  = k0 + jq * 4 + e;
            int kb = k >> 6, kr = k & 63;
            int off = kb * 16384 + kr * 128 + ((ib ^ (kr & 7)) << 4) + 2 * ie;
            ushort h  = *(const ushort*)(sm + off);
            ushort lo = *(const ushort*)(sm + off + 8192);
            ((float*)&v)[e] = __uint_as_float((uint)h << 16) + __uint_as_float((uint)lo << 16);
        }
        *(float4*)(arow + jq * 4) = v;
    }
}

// ---- update (fast): A staged via LDS (deduped 4x wave redundancy), X reg-direct ----
__global__ __launch_bounds__(256, 3) void update_mfma(const char* __restrict__ Aimg,
                                                      const char* __restrict__ Ximg,
                                                      float* __restrict__ part,
                                                      int S,
                                                      const float* __restrict__ diffStop) {
    if (*diffStop <= THRESH) return;
    __shared__ __align__(16) char smem[32768];   // A double-buffer: 2 x 16KB
    const int f  = blockIdx.x;
    // XCD-grouping: the 16 tile-blocks (kb x db) sharing a z-chunk get
    // consecutive-mod-8-equal blockIdx -> same XCD -> shared A/X pages L2-hit.
    const int z  = f % S;
    const int t  = f / S;
    const int kb = t & 3;
    const int db = t >> 2;
    const int steps = 512 / S;
    const int tid = threadIdx.x;
    const int w   = tid >> 6;
    const int l   = tid & 63;
    const int lw  = l & 15;
    const int lg  = l >> 4;
    const char* Abase = Aimg + (((size_t)kb * 512 + (size_t)z * steps) << 14);
    const char* Xbase = Ximg + (((size_t)db * 512 + (size_t)z * steps) << 15);

    floatx4 acc[4][2];
    #pragma unroll
    for (int a = 0; a < 4; ++a)
        #pragma unroll
        for (int b = 0; b < 2; ++b) acc[a][b] = (floatx4){0.f, 0.f, 0.f, 0.f};

    // prologue: A(0) -> buf0
    #pragma unroll
    for (int j = 0; j < 4; ++j)
        GLL(Abase + j * 4096 + tid * 16, smem + j * 4096 + tid * 16);

    for (int st = 0; st < steps; ++st) {
        const int cur = (st & 1) ? 16384 : 0;
        const int nxt = (st & 1) ? 0 : 16384;
        const char* Xp = Xbase + ((size_t)st << 15);
        // X fragments (per-wave unique) -> registers, both ks halves
        short8 bh[2][2], bl[2][2];
        #pragma unroll
        for (int ks = 0; ks < 2; ++ks) {
            int bc = 64 * ks + 16 * lg;
            #pragma unroll
            for (int cb = 0; cb < 2; ++cb) {
                int rd = w * 32 + cb * 16 + lw;
                int off = rd * 128 + SWZ(rd, bc);
                bh[ks][cb] = *(const short8*)(Xp + off);
                bl[ks][cb] = *(const short8*)(Xp + 16384 + off);
            }
        }
        if (st + 1 < steps) {
            const char* Ap = Abase + ((size_t)(st + 1) << 14);
            #pragma unroll
            for (int j = 0; j < 4; ++j)
                GLL(Ap + j * 4096 + tid * 16, smem + nxt + j * 4096 + tid * 16);
            // drain A(st) + X(st); keep A(st+1)'s 4 GLLs in flight
            asm volatile("s_waitcnt vmcnt(4)" ::: "memory");
        } else {
            asm volatile("s_waitcnt vmcnt(0)" ::: "memory");
        }
        __builtin_amdgcn_s_barrier();
        #pragma unroll
        for (int ks = 0; ks < 2; ++ks) {
            int bc = 64 * ks + 16 * lg;
            short8 ah[4], al[4];
            #pragma unroll
            for (int rb = 0; rb < 4; ++rb) {
                int r = rb * 16 + lw;
                int off = r * 128 + SWZ(r, bc);
                ah[rb] = *(const short8*)(smem + cur + off);
                al[rb] = *(const short8*)(smem + cur + 8192 + off);
            }
            __builtin_amdgcn_s_setprio(1);
            #pragma unroll
            for (int cb = 0; cb < 2; ++cb) {
                #pragma unroll
                for (int rb = 0; rb < 4; ++rb)
                    acc[rb][cb] = __builtin_amdgcn_mfma_f32_16x16x32_bf16(ah[rb], bh[ks][cb], acc[rb][cb], 0, 0, 0);
                #pragma unroll
                for (int rb = 0; rb < 4; ++rb)
                    acc[rb][cb] = __builtin_amdgcn_mfma_f32_16x16x32_bf16(ah[rb], bl[ks][cb], acc[rb][cb], 0, 0, 0);
                #pragma unroll
                for (int rb = 0; rb < 4; ++rb)
                    acc[rb][cb] = __builtin_amdgcn_mfma_f32_16x16x32_bf16(al[rb], bh[ks][cb], acc[rb][cb], 0, 0, 0);
            }
            __builtin_amdgcn_s_setprio(0);
        }
        asm volatile("s_waitcnt lgkmcnt(0)" ::: "memory");
        __builtin_amdgcn_s_barrier();
    }

    float* pb = part + (size_t)z * (KC * DIM);
    #pragma unroll
    for (int rb = 0; rb < 4; ++rb)
        #pragma unroll
        for (int cb = 0; cb < 2; ++cb) {
            int kbr = kb * 64 + rb * 16 + lg * 4;
            int d   = db * 128 + w * 32 + cb * 16 + lw;
            #pragma unroll
            for (int j = 0; j < 4; ++j)
                pb[(size_t)(kbr + j) * DIM + d] = acc[rb][cb][j];
        }
}

// ---------------- update (f32 fallback) ----------------
#define UIC  32
#define ALD  68
#define XLD2 136

__global__ __launch_bounds__(256) void update_f32(const float* __restrict__ A,
                                                  const float* __restrict__ X,
                                                  float* __restrict__ part,
                                                  int ichunk,
                                                  const int* __restrict__ stop) {
    if (*stop) return;
    __shared__ __align__(16) float As[UIC][ALD];
    __shared__ __align__(16) float Xs[UIC][XLD2];
    const int tid  = threadIdx.x;
    const int tk   = tid & 15;
    const int td   = tid >> 4;
    const int k0   = blockIdx.x * 64;
    const int d0   = blockIdx.y * 128;
    const int ibeg = blockIdx.z * ichunk;

    float acc[4][8];
    #pragma unroll
    for (int a = 0; a < 4; ++a)
        #pragma unroll
        for (int b = 0; b < 8; ++b) acc[a][b] = 0.f;

    for (int ii = 0; ii < ichunk; ii += UIC) {
        __syncthreads();
        #pragma unroll
        for (int e = tid; e < UIC * 64; e += 256) {
            int k = e & 63, i = e >> 6;
            As[i][k] = A[(size_t)(ibeg + ii + i) * KC + k0 + k];
        }
        #pragma unroll
        for (int e = tid; e < UIC * 128; e += 256) {
            int d = e & 127, i = e >> 7;
            Xs[i][d] = X[(size_t)(ibeg + ii + i) * DIM + d0 + d];
        }
        __syncthreads();
        #pragma unroll 4
        for (int i = 0; i < UIC; ++i) {
            float av[4], xv[8];
            *(float4*)av      = *(const float4*)&As[i][tk * 4];
            *(float4*)&xv[0]  = *(const float4*)&Xs[i][td * 8];
            *(float4*)&xv[4]  = *(const float4*)&Xs[i][td * 8 + 4];
            #pragma unroll
            for (int a = 0; a < 4; ++a)
                #pragma unroll
                for (int b = 0; b < 8; ++b)
                    acc[a][b] = fmaf(av[a], xv[b], acc[a][b]);
        }
    }
    float* pb = part + (size_t)blockIdx.z * (KC * DIM);
    #pragma unroll
    for (int a = 0; a < 4; ++a) {
        float* prow = pb + (size_t)(k0 + tk * 4 + a) * DIM + d0 + td * 8;
        *(float4*)&prow[0] = *(float4*)&acc[a][0];
        *(float4*)&prow[4] = *(float4*)&acc[a][4];
    }
}

// -- reduce_fused (fast): float4-vectorized; Cnext, diff + next-iter prep --
__global__ __launch_bounds__(256) void reduce_fused(const float* __restrict__ part,
                                                    const float* __restrict__ a_sumR,
                                                    const float* __restrict__ Cprev,
                                                    float* __restrict__ Cnext,
                                                    float* __restrict__ c2W,
                                                    float* __restrict__ c2Z,
                                                    float* __restrict__ a_sumZ,
                                                    float* __restrict__ diffR,
                                                    const float* __restrict__ diffStop,
                                                    char* __restrict__ Cimg,
                                                    int S) {
    if (*diffStop <= THRESH) return;
    const int tid = threadIdx.x;
    const int idx4 = blockIdx.x * 256 + tid;     // grid 128 blocks, 4 floats/thread
    const int idx  = idx4 * 4;
    float4 s = {0.f, 0.f, 0.f, 0.f};
    for (int p = 0; p < S; ++p) {
        float4 v = *(const float4*)&part[(size_t)p * (KC * DIM) + idx];
        s.x += v.x; s.y += v.y; s.z += v.z; s.w += v.w;
    }
    int k = idx >> 9;
    float den = a_sumR[k] + EPS_F;
    float4 v4;
    v4.x = s.x / den; v4.y = s.y / den; v4.z = s.z / den; v4.w = s.w / den;
    *(float4*)&Cnext[idx] = v4;
    // next-iter prep: bf16 hi/lo into C-image (4 consecutive d share one 16B slot)
    {
        int d = idx & 511;
        ushort4 h, lo;
        f2bf2(v4.x, h.x, lo.x);
        f2bf2(v4.y, h.y, lo.y);
        f2bf2(v4.z, h.z, lo.z);
        f2bf2(v4.w, h.w, lo.w);
        char* cb = Cimg + (d >> 6) * 65536 + k * 128
                 + ((((d >> 3) & 7) ^ (k & 7)) << 4) + (d & 7) * 2;
        *(ushort4*)cb           = h;
        *(ushort4*)(cb + 32768) = lo;
    }
    // zero ping-pong buffers for iter t+1 (safe: their readers/writers all done)
    if (blockIdx.x == 1) a_sumZ[tid] = 0.f;
    if (blockIdx.x == 2) c2Z[tid] = 0.f;
    // diff partial + c2 partial (wave covers 256 consecutive d within one k)
    float4 cp = *(const float4*)&Cprev[idx];
    float d = fabsf(v4.x - cp.x) + fabsf(v4.y - cp.y)
            + fabsf(v4.z - cp.z) + fabsf(v4.w - cp.w);
    float vv = v4.x*v4.x + v4.y*v4.y + v4.z*v4.z + v4.w*v4.w;
    #pragma unroll
    for (int o = 32; o; o >>= 1) { d += __shfl_xor(d, o); vv += __shfl_xor(vv, o); }
    if ((tid & 63) == 0) {
        atomicAdd(diffR, d);
        atomicAdd(&c2W[k], vv);
    }
}

// -- reduce (slow fallback): as before --
__global__ __launch_bounds__(256) void reduce_slow(const float* __restrict__ part,
                                                   const float* __restrict__ a_sum,
                                                   const float* __restrict__ Cin,
                                                   float* __restrict__ Cout,
                                                   float* __restrict__ diff,
                                                   int* __restrict__ counter,
                                                   int* __restrict__ stop,
                                                   int S) {
    if (*stop) return;
    int idx = blockIdx.x * 256 + threadIdx.x;
    float s = 0.f;
    for (int p = 0; p < S; ++p) s += part[(size_t)p * (KC * DIM) + idx];
    int k = idx >> 9;
    float v = s / (a_sum[k] + EPS_F);
    Cout[idx] = v;
    float d = fabsf(v - Cin[idx]);
    #pragma unroll
    for (int o = 32; o; o >>= 1) d += __shfl_xor(d, o);
    if ((threadIdx.x & 63) == 0) atomicAdd(diff, d);
    __syncthreads();
    if (threadIdx.x == 0) {
        __threadfence();
        int done = atomicAdd(counter, 1);
        if (done == (int)gridDim.x - 1) {
            __threadfence();
            float dv = atomicAdd(diff, 0.f);
            if (dv <= THRESH) *stop = 1;
            *counter = 0;
        }
    }
}

extern "C" void kernel_launch(void* const* d_in, const int* in_sizes, int n_in,
                              void* d_out, int out_size, void* d_ws, size_t ws_size,
                              hipStream_t stream) {
    const float* X     = (const float*)d_in[0];
    const float* Cinit = (const float*)d_in[1];
    float* out = (float*)d_out;
    float* outC = out;                 // [256*512]
    float* A    = out + KC * DIM;      // [32768*256]

    char* p = (char*)d_ws;
    float* x2      = (float*)p;  p += NPTS * 4;
    float* c2b0    = (float*)p;  p += 1024;
    float* c2b1    = (float*)p;  p += 1024;
    float* asum0   = (float*)p;  p += 1024;
    float* asum1   = (float*)p;  p += 1024;
    float* diffp   = (float*)p;          // diff[0]@0, diff[1]@4
    int*   stop    = (int*)(p + 16);
    int*   counter = (int*)(p + 20);  p += 64;
    float* CoutA   = (float*)p;  p += (size_t)KC * DIM * 4;
    float* CoutB   = (float*)p;  p += (size_t)KC * DIM * 4;
    ushort* Chg    = (ushort*)p; p += (size_t)KC * DIM * 2;
    ushort* Clg    = (ushort*)p; p += (size_t)KC * DIM * 2;
    char* Cimg     = p;          p += 524288;
    char* planes = p;
    char* Ximg   = p;          p += (size_t)4 * 512 * XPAY;   // 64 MB
    char* Aimg   = p;          p += (size_t)4 * 512 * APAY;   // 32 MB
    float* partF = (float*)p;
    char* Xrow   = p + (size_t)32 * KC * DIM * 4;             // after S=32 part (16 MB)
    float* partS = (float*)planes;

    size_t fixedS  = (size_t)(planes - (char*)d_ws);
    size_t needT2  = (size_t)(Xrow - (char*)d_ws) + (size_t)512 * 8 * 16384;  // + 64MB
    const size_t PART1 = (size_t)KC * DIM * 4;
    bool tier2 = ws_size >= needT2;
    int S = 32;
    if (!tier2) { while (S > 1 && fixedS + (size_t)S * PART1 > ws_size) S >>= 1; }
    int ichunk = NPTS / S;
    float* part = tier2 ? partF : partS;

    x2_kernel<<<NPTS / 4, 256, 0, stream>>>(X, x2, stop, counter);
    if (tier2) {
        xpose_kernel<<<dim3(NPTS / 64, DIM / 64), 256, 0, stream>>>(X, Ximg, Xrow);
        prep0_kernel<<<KC, 64, 0, stream>>>(Cinit, CoutA, Cimg, c2b0, c2b1, asum0, diffp);
        for (int t = 0; t < 26; ++t) {
            int par = t & 1;
            float* c2R   = par ? c2b1 : c2b0;
            float* c2Wn  = par ? c2b0 : c2b1;
            float* asR   = par ? asum1 : asum0;
            float* asZ   = par ? asum0 : asum1;
            float* Cuse  = par ? CoutB : CoutA;
            float* Cnext = par ? CoutA : CoutB;
            float* dStop = diffp + (par ^ 1);   // diff from iter t-1 (sentinel at t=0)
            float* dAcc  = diffp + par;         // zeroed by assign, accumulated by reduce
            assign_fast<<<NPTS / 128, 512, 0, stream>>>(Cimg, Xrow,
                                                        x2, c2R, asR, Aimg, Cuse, outC,
                                                        dStop, dAcc);
            update_mfma<<<16 * S, 256, 0, stream>>>(Aimg, Ximg, part, S, dStop);
            reduce_fused<<<KC * DIM / 1024, 256, 0, stream>>>(part, asR, Cuse, Cnext,
                                                              c2Wn, c2R, asZ,
                                                              dAcc, dStop, Cimg, S);
        }
        emit_kernel<<<512, 256, 0, stream>>>(Aimg, A);
    } else {
        for (int t = 0; t < 26; ++t) {
            prep_kernel<<<KC, 64, 0, stream>>>(t == 0 ? Cinit : CoutB, outC, Chg, Clg,
                                               c2b0, asum0, diffp, stop);
            assign_slow<<<NPTS / 64, 256, 0, stream>>>(X, Chg, Clg, x2, c2b0, A, asum0, stop);
            update_f32<<<dim3(KC / 64, DIM / 128, S), 256, 0, stream>>>(A, X, part, ichunk, stop);
            reduce_slow<<<KC * DIM / 256, 256, 0, stream>>>(part, asum0, outC, CoutB,
                                                            diffp, counter, stop, S);
        }
    }
}